// Round 6
// baseline (136.779 us; speedup 1.0000x reference)
//
#include <hip/hip_runtime.h>
#include <hip/hip_bf16.h>
#include <stdint.h>

// VQ-VAE vector quantizer forward, MI355X (gfx950).
// z: [32,256,32,32] fp32 (NCHW), E: [1024,256] fp32.
// score(n,k) = 0.5*||e_k||^2 - <f_n,e_k>  (argmin-equivalent to d2)
// dots via bf16 MFMA 16x16x32 fp32-accum; losses/gather exact fp32.
//
// R6: k_main = 512 blocks x 256 thr (4 waves), 64 rows/block, 16 rows/wave.
// 2 blocks/CU (independent barrier domains — R3..R5 all had one barrier
// domain per CU, so every per-chunk vmcnt(0) drain stalled the whole CU).
// Chunk = 32 codes (16 KB), double-buffered global_load_lds from pre-
// swizzled Esw; explicit 1-ahead register pipeline on B-fragments.

typedef short v8s __attribute__((ext_vector_type(8)));
typedef float v4f __attribute__((ext_vector_type(4)));

__device__ inline unsigned short f2bf(float f) {  // RNE fp32->bf16
    uint32_t u = __float_as_uint(f);
    return (unsigned short)((u + 0x7fffu + ((u >> 16) & 1u)) >> 16);
}

// ---- Kernel 1: z (NCHW fp32) -> Abf[n][d] bf16, register-only transpose ----
__global__ __launch_bounds__(512) void k_prep_a(const float* __restrict__ z,
                                                unsigned short* __restrict__ Abf) {
    int tid = threadIdx.x;
    int b = blockIdx.x >> 4, hw0 = (blockIdx.x & 15) << 6;
    int t15 = tid & 15, dblk = tid >> 4;            // hwq = 4*t15, d0 = 8*dblk
    const float* zp = z + ((size_t)b << 18) + (size_t)(dblk << 3) * 1024 + hw0 + (t15 << 2);
    float4 L[8];
#pragma unroll
    for (int j = 0; j < 8; j++)
        L[j] = *(const float4*)(zp + (size_t)j * 1024);
    const float* Lf = (const float*)L;
    v8s* Aout = (v8s*)Abf + ((size_t)(b * 1024 + hw0 + (t15 << 2))) * 32 + dblk;
#pragma unroll
    for (int c = 0; c < 4; c++) {
        union { v8s v; unsigned short s[8]; } u;
#pragma unroll
        for (int j = 0; j < 8; j++) u.s[j] = f2bf(Lf[j * 4 + c]);
        Aout[(size_t)c * 32] = u.v;
    }
}

// ---- Kernel 2: E -> SWIZZLED Ebf bf16 + nE + accum=0 -----------------------
// Unit for (k, dc, g): U = (k>>4)*512 + dc*64 + g*16 + (k&15),
// holding elems d = dc*32 + g*8 .. +8. Coalesced 16B stores.
__global__ __launch_bounds__(256) void k_prep_e(const float* __restrict__ E,
                                                v8s* __restrict__ Esw,
                                                float* __restrict__ nE,
                                                float* __restrict__ accum) {
    __shared__ float Ef[16][264];
    int q = blockIdx.x, tid = threadIdx.x;
    const float4* Ein = (const float4*)(E + ((size_t)q << 12));
#pragma unroll
    for (int i = 0; i < 4; i++) {
        int f4 = i * 256 + tid;
        int row = f4 >> 6, c4 = (f4 & 63) << 2;
        *(float4*)&Ef[row][c4] = Ein[f4];
    }
    __syncthreads();
    {
        int c = tid >> 4, l = tid & 15;
        float s = 0.f;
#pragma unroll
        for (int j = 0; j < 16; j++) { float v = Ef[c][l + 16 * j]; s += v * v; }
#pragma unroll
        for (int off = 1; off < 16; off <<= 1) s += __shfl_xor(s, off);
        if (l == 0) nE[q * 16 + c] = 0.5f * s;
    }
#pragma unroll
    for (int i = 0; i < 2; i++) {
        int u = tid + i * 256;
        int um = u & 15, ug = (u >> 4) & 3, udc = (u >> 6) & 7;
        int d0 = udc * 32 + ug * 8;
        union { v8s v; unsigned short s[8]; } pk;
#pragma unroll
        for (int e = 0; e < 8; e++) pk.s[e] = f2bf(Ef[um][d0 + e]);
        Esw[((size_t)q << 9) + u] = pk.v;
    }
    if (q == 0 && tid == 0) accum[0] = 0.f;
}

// ---- Kernel 3: fused GEMM+argmin+gather+output+loss -------------------------
__global__ __launch_bounds__(256, 2) void k_main(
        const unsigned short* __restrict__ Abf,
        const v8s* __restrict__ Esw,
        const float* __restrict__ nE,
        const float* __restrict__ z,
        const float* __restrict__ E,
        float* __restrict__ out,
        float* __restrict__ accum) {
    __shared__ union {
        v8s    B[2][1024];          // 2 x 16 KB double-buffer (32 codes/chunk)
        float4 Eg4[2048];           // epilogue swizzled tile (32 KB)
    } S;
    __shared__ float nEl[1024];
    __shared__ int   idxLds[64];
    __shared__ float w4[4];

    int tid = threadIdx.x;
    int lane = tid & 63, w = tid >> 6;         // 4 waves
    int g = lane >> 4, m = lane & 15;          // MFMA lane coords
    int R0 = blockIdx.x << 6;                  // 64 rows/block
    int b = R0 >> 10;

#pragma unroll
    for (int i = 0; i < 4; i++) nEl[tid + i * 256] = nE[tid + i * 256];

    // A frags: 16 rows/wave, read once
    v8s a[8];
    {
        const v8s* Ap = (const v8s*)Abf;
        int row = R0 + w * 16 + m;
#pragma unroll
        for (int dc = 0; dc < 8; dc++)
            a[dc] = Ap[(size_t)row * 32 + dc * 4 + g];
    }

    // staging: chunk = 1024 v8s (16 KB); thread stages units j*256+tid
#define STAGE(ch, buf)                                                        \
    {                                                                         \
        _Pragma("unroll")                                                     \
        for (int j = 0; j < 4; j++) {                                         \
            __builtin_amdgcn_global_load_lds(                                 \
                (const __attribute__((address_space(1))) void*)               \
                    (Esw + ((size_t)(ch) << 10) + (j << 8) + (w << 6) + lane),\
                (__attribute__((address_space(3))) void*)                     \
                    &S.B[buf][(j << 8) + (w << 6)],                           \
                16, 0, 0);                                                    \
        }                                                                     \
    }

    float best[4]; int bidx[4];
#pragma unroll
    for (int r = 0; r < 4; r++) { best[r] = 3.4e38f; bidx[r] = 0; }

    STAGE(0, 0);
#pragma unroll 1
    for (int ct = 0; ct < 32; ct++) {
        int cur = ct & 1;
        __syncthreads();                       // chunk ct resident
        if (ct < 31) STAGE(ct + 1, cur ^ 1);
        float ne0 = nEl[(ct << 5) + m];
        float ne1 = nEl[(ct << 5) + 16 + m];
        v4f acc0 = {0.f, 0.f, 0.f, 0.f}, acc1 = {0.f, 0.f, 0.f, 0.f};
        int base = g * 16 + m;
        // explicit 1-ahead register pipeline over dc
        v8s bf0 = S.B[cur][base];
        v8s bf1 = S.B[cur][512 + base];
#pragma unroll
        for (int dc = 0; dc < 8; dc++) {
            v8s nf0, nf1;
            if (dc < 7) {
                nf0 = S.B[cur][(dc + 1) * 64 + base];
                nf1 = S.B[cur][512 + (dc + 1) * 64 + base];
            }
            acc0 = __builtin_amdgcn_mfma_f32_16x16x32_bf16(a[dc], bf0, acc0, 0, 0, 0);
            acc1 = __builtin_amdgcn_mfma_f32_16x16x32_bf16(a[dc], bf1, acc1, 0, 0, 0);
            bf0 = nf0; bf1 = nf1;
        }
        int code = (ct << 5) + m;              // C/D col = lane&15
#pragma unroll
        for (int r = 0; r < 4; r++) {
            float s0 = ne0 - acc0[r];
            if (s0 < best[r]) { best[r] = s0; bidx[r] = code; }
            float s1 = ne1 - acc1[r];
            if (s1 < best[r]) { best[r] = s1; bidx[r] = code + 16; }
        }
    }

    // winner reduce over 16 code-columns (pack: min => low score, low idx)
#pragma unroll
    for (int r = 0; r < 4; r++) {
        uint32_t sb = __float_as_uint(best[r]);
        sb = (sb & 0x80000000u) ? ~sb : (sb | 0x80000000u);
        unsigned long long pk = ((unsigned long long)sb << 32) | (uint32_t)bidx[r];
#pragma unroll
        for (int off = 1; off < 16; off <<= 1) {
            unsigned long long o = __shfl_xor(pk, off);
            if (o < pk) pk = o;
        }
        if (m == 0)                            // C/D row = g*4 + r
            idxLds[w * 16 + g * 4 + r] = (int)(pk & 0xffffffffu);
    }
    __syncthreads();                           // winners visible; B free

    // epilogue: 2 phases of 32 rows through XOR-swizzled float4 tile.
    float lsum = 0.f;
    const float* zb = z + ((size_t)b << 18);
    float* ob = out + ((size_t)b << 18);
    int hwl = tid & 31, dq0 = tid >> 5;        // dq0: 0..7
#pragma unroll 1
    for (int ph = 0; ph < 2; ph++) {
#pragma unroll
        for (int i = 0; i < 8; i++) {          // rows w + 4i (wave-uniform)
            int row = w + (i << 2);
            int k = idxLds[(ph << 5) + row];
            float4 v = ((const float4*)(E + ((size_t)k << 8)))[lane];
            S.Eg4[(row << 6) + (lane ^ row)] = v;
        }
        __syncthreads();
        int hwp = (R0 & 1023) + (ph << 5) + hwl;
#pragma unroll
        for (int i = 0; i < 8; i++) {
            int dq = dq0 + (i << 3);
            float4 ev = S.Eg4[(hwl << 6) + (dq ^ hwl)];
            size_t o = ((size_t)dq << 12) + hwp;        // (4*dq)*1024 + hwp
            float z0 = zb[o], z1 = zb[o + 1024], z2 = zb[o + 2048], z3 = zb[o + 3072];
            ob[o] = ev.x; ob[o + 1024] = ev.y; ob[o + 2048] = ev.z; ob[o + 3072] = ev.w;
            float dx = ev.x - z0, dy = ev.y - z1, dz2 = ev.z - z2, dw = ev.w - z3;
            lsum += dx * dx + dy * dy + dz2 * dz2 + dw * dw;
        }
        __syncthreads();                        // tile reused next phase
    }
#pragma unroll
    for (int off = 1; off < 64; off <<= 1) lsum += __shfl_xor(lsum, off);
    if (lane == 0) w4[w] = lsum;
    __syncthreads();
    if (tid == 0) atomicAdd(accum, w4[0] + w4[1] + w4[2] + w4[3]);
#undef STAGE
}

// ---- Kernel 4: scalar outputs ----------------------------------------------
__global__ void k_loss(const float* __restrict__ accum, float* __restrict__ out) {
    if (threadIdx.x == 0) {
        float s = accum[0] * (1.0f / 8388608.0f);
        out[8388608] = 1.25f * s;
        out[8388609] = s;
        out[8388610] = s;
    }
}

extern "C" void kernel_launch(void* const* d_in, const int* in_sizes, int n_in,
                              void* d_out, int out_size, void* d_ws, size_t ws_size,
                              hipStream_t stream) {
    const float* z = (const float*)d_in[0];
    const float* E = (const float*)d_in[1];
    char* ws = (char*)d_ws;
    unsigned short* Abf   = (unsigned short*)(ws);               // 16,777,216 B
    v8s*            Esw   = (v8s*)(ws + 16777216);               //    524,288 B
    float*          nE    = (float*)(ws + 17301504);             //      4,096 B
    float*          accum = (float*)(ws + 17305600);             //          4 B
    float* out = (float*)d_out;

    hipLaunchKernelGGL(k_prep_e, dim3(64),  dim3(256), 0, stream, E, Esw, nE, accum);
    hipLaunchKernelGGL(k_prep_a, dim3(512), dim3(512), 0, stream, z, Abf);
    hipLaunchKernelGGL(k_main,   dim3(512), dim3(256), 0, stream,
                       Abf, Esw, nE, z, E, out, accum);
    hipLaunchKernelGGL(k_loss,   dim3(1),   dim3(64),  0, stream, accum, out);
}

// Round 7
// 135.482 us; speedup vs baseline: 1.0096x; 1.0096x over previous
//
#include <hip/hip_runtime.h>
#include <hip/hip_bf16.h>
#include <stdint.h>

// VQ-VAE vector quantizer forward, MI355X (gfx950).
// z: [32,256,32,32] fp32 (NCHW), E: [1024,256] fp32.
// score(n,k) = 0.5*||e_k||^2 - <f_n,e_k>  (argmin-equivalent to d2)
// dots via bf16 MFMA 16x16x32 fp32-accum; losses/gather exact fp32.
//
// R7 k_main: 512 blocks = 128 row-groups x 4 code-splits; 256 thr (4 waves).
// Wave holds 64 rows (4 sets) of A in registers -> each LDS B-read feeds 4
// MFMAs (R=4: ds_read/CU 1024 b128 ~5.1us < MFMA 8.3us). Codes stream in 4
// chunks of 64 (2x32KB dbuf, 5 barriers total). Per-split winners -> cand;
// k_out combines + gathers + writes NCHW + loss.

typedef short v8s __attribute__((ext_vector_type(8)));
typedef float v4f __attribute__((ext_vector_type(4)));

__device__ inline unsigned short f2bf(float f) {  // RNE fp32->bf16
    uint32_t u = __float_as_uint(f);
    return (unsigned short)((u + 0x7fffu + ((u >> 16) & 1u)) >> 16);
}

// ---- Kernel 1: z (NCHW fp32) -> Abf[n][d] bf16, register-only transpose ----
__global__ __launch_bounds__(512) void k_prep_a(const float* __restrict__ z,
                                                unsigned short* __restrict__ Abf) {
    int tid = threadIdx.x;
    int b = blockIdx.x >> 4, hw0 = (blockIdx.x & 15) << 6;
    int t15 = tid & 15, dblk = tid >> 4;            // hwq = 4*t15, d0 = 8*dblk
    const float* zp = z + ((size_t)b << 18) + (size_t)(dblk << 3) * 1024 + hw0 + (t15 << 2);
    float4 L[8];
#pragma unroll
    for (int j = 0; j < 8; j++)
        L[j] = *(const float4*)(zp + (size_t)j * 1024);
    const float* Lf = (const float*)L;
    v8s* Aout = (v8s*)Abf + ((size_t)(b * 1024 + hw0 + (t15 << 2))) * 32 + dblk;
#pragma unroll
    for (int c = 0; c < 4; c++) {
        union { v8s v; unsigned short s[8]; } u;
#pragma unroll
        for (int j = 0; j < 8; j++) u.s[j] = f2bf(Lf[j * 4 + c]);
        Aout[(size_t)c * 32] = u.v;
    }
}

// ---- Kernel 2: E -> SWIZZLED Ebf bf16 + nE + accum=0 -----------------------
// Unit for (k, dc, g): U = (k>>4)*512 + dc*64 + g*16 + (k&15),
// holding elems d = dc*32 + g*8 .. +8. Coalesced 16B stores.
__global__ __launch_bounds__(256) void k_prep_e(const float* __restrict__ E,
                                                v8s* __restrict__ Esw,
                                                float* __restrict__ nE,
                                                float* __restrict__ accum) {
    __shared__ float Ef[16][264];
    int q = blockIdx.x, tid = threadIdx.x;
    const float4* Ein = (const float4*)(E + ((size_t)q << 12));
#pragma unroll
    for (int i = 0; i < 4; i++) {
        int f4 = i * 256 + tid;
        int row = f4 >> 6, c4 = (f4 & 63) << 2;
        *(float4*)&Ef[row][c4] = Ein[f4];
    }
    __syncthreads();
    {
        int c = tid >> 4, l = tid & 15;
        float s = 0.f;
#pragma unroll
        for (int j = 0; j < 16; j++) { float v = Ef[c][l + 16 * j]; s += v * v; }
#pragma unroll
        for (int off = 1; off < 16; off <<= 1) s += __shfl_xor(s, off);
        if (l == 0) nE[q * 16 + c] = 0.5f * s;
    }
#pragma unroll
    for (int i = 0; i < 2; i++) {
        int u = tid + i * 256;
        int um = u & 15, ug = (u >> 4) & 3, udc = (u >> 6) & 7;
        int d0 = udc * 32 + ug * 8;
        union { v8s v; unsigned short s[8]; } pk;
#pragma unroll
        for (int e = 0; e < 8; e++) pk.s[e] = f2bf(Ef[um][d0 + e]);
        Esw[((size_t)q << 9) + u] = pk.v;
    }
    if (q == 0 && tid == 0) accum[0] = 0.f;
}

// ---- Kernel 3: MFMA GEMM + per-split argmin (R=4 A-reuse) ------------------
__global__ __launch_bounds__(256, 2) void k_main(
        const unsigned short* __restrict__ Abf,
        const v8s* __restrict__ Esw,
        const float* __restrict__ nE,
        unsigned long long* __restrict__ cand) {
    __shared__ v8s B[2][2048];                 // 2 x 32 KB double-buffer
    __shared__ float nEl[256];

    int tid = threadIdx.x;
    int lane = tid & 63, w = tid >> 6;         // 4 waves
    int g = lane >> 4, m = lane & 15;          // MFMA lane coords
    int cs = blockIdx.x & 3;                   // code split
    int R0 = (blockIdx.x >> 2) << 8;           // 256 rows/block
    int C0 = cs << 8;                          // 256 codes/block

    nEl[tid] = nE[C0 + tid];

    // A frags: 64 rows/wave (4 sets of 16), held in registers for the kernel
    v8s a[4][8];
    {
        const v8s* Ap = (const v8s*)Abf;
#pragma unroll
        for (int s = 0; s < 4; s++) {
            int row = R0 + (w << 6) + (s << 4) + m;
#pragma unroll
            for (int dc = 0; dc < 8; dc++)
                a[s][dc] = Ap[(size_t)row * 32 + dc * 4 + g];
        }
    }

    // stage chunk ch (64 codes = 2048 v8s = 32 KB): contiguous, 8/thread
#define STAGE(ch, buf)                                                        \
    {                                                                         \
        _Pragma("unroll")                                                     \
        for (int j = 0; j < 8; j++) {                                         \
            __builtin_amdgcn_global_load_lds(                                 \
                (const __attribute__((address_space(1))) void*)               \
                    (Esw + ((size_t)(C0 + (ch) * 64) << 5) + (j << 8)         \
                         + (w << 6) + lane),                                  \
                (__attribute__((address_space(3))) void*)                     \
                    &B[buf][(j << 8) + (w << 6)],                             \
                16, 0, 0);                                                    \
        }                                                                     \
    }

    float best[4][4]; int bidx[4][4];
#pragma unroll
    for (int s = 0; s < 4; s++)
#pragma unroll
        for (int r = 0; r < 4; r++) { best[s][r] = 3.4e38f; bidx[s][r] = 0; }

    STAGE(0, 0);
#pragma unroll 1
    for (int ct = 0; ct < 4; ct++) {           // only 4 chunks -> 5 barriers
        int cur = ct & 1;
        __syncthreads();                       // chunk ct resident
        if (ct < 3) STAGE(ct + 1, cur ^ 1);
#pragma unroll
        for (int t = 0; t < 4; t++) {          // col-tiles of 16 codes
            float ne = nEl[(ct << 6) + (t << 4) + m];
            v4f acc[4];
#pragma unroll
            for (int s = 0; s < 4; s++) acc[s] = (v4f){0.f, 0.f, 0.f, 0.f};
#pragma unroll
            for (int dc = 0; dc < 8; dc++) {   // one B-read feeds 4 MFMAs
                v8s bf = B[cur][(t << 9) + (dc << 6) + (g << 4) + m];
                acc[0] = __builtin_amdgcn_mfma_f32_16x16x32_bf16(a[0][dc], bf, acc[0], 0, 0, 0);
                acc[1] = __builtin_amdgcn_mfma_f32_16x16x32_bf16(a[1][dc], bf, acc[1], 0, 0, 0);
                acc[2] = __builtin_amdgcn_mfma_f32_16x16x32_bf16(a[2][dc], bf, acc[2], 0, 0, 0);
                acc[3] = __builtin_amdgcn_mfma_f32_16x16x32_bf16(a[3][dc], bf, acc[3], 0, 0, 0);
            }
            int code = C0 + (ct << 6) + (t << 4) + m;   // C/D col = lane&15
#pragma unroll
            for (int s = 0; s < 4; s++)
#pragma unroll
                for (int r = 0; r < 4; r++) {
                    float sc = ne - acc[s][r];
                    if (sc < best[s][r]) { best[s][r] = sc; bidx[s][r] = code; }
                }
        }
    }

    // winner reduce over 16 code-columns (pack: min => low score, low idx)
#pragma unroll
    for (int s = 0; s < 4; s++)
#pragma unroll
        for (int r = 0; r < 4; r++) {
            uint32_t sb = __float_as_uint(best[s][r]);
            sb = (sb & 0x80000000u) ? ~sb : (sb | 0x80000000u);
            unsigned long long pk = ((unsigned long long)sb << 32) | (uint32_t)bidx[s][r];
#pragma unroll
            for (int off = 1; off < 16; off <<= 1) {
                unsigned long long o = __shfl_xor(pk, off);
                if (o < pk) pk = o;
            }
            if (m == 0)                        // C/D row = g*4 + r
                cand[((size_t)cs << 15) + R0 + (w << 6) + (s << 4) + (g << 2) + r] = pk;
        }
#undef STAGE
}

// ---- Kernel 4: combine splits + gather + NCHW write + loss -----------------
__global__ __launch_bounds__(256) void k_out(const float* __restrict__ z,
                                             const float* __restrict__ E,
                                             const unsigned long long* __restrict__ cand,
                                             float* __restrict__ out,
                                             float* __restrict__ accum) {
    __shared__ float4 Eg4[2048];               // XOR-swizzled 32x64 tile, 32 KB
    __shared__ int    kk[32];
    __shared__ float  w4[4];
    int bid = blockIdx.x;
    int b = bid >> 5, hw0 = (bid & 31) << 5;
    int tid = threadIdx.x;
    int lane = tid & 63, w = tid >> 6;
    if (tid < 32) {
        int n = b * 1024 + hw0 + tid;
        unsigned long long bv = cand[n];
#pragma unroll
        for (int s = 1; s < 4; s++) {
            unsigned long long v = cand[((size_t)s << 15) + n];
            if (v < bv) bv = v;
        }
        kk[tid] = (int)(bv & 0xffffffffu);
    }
    __syncthreads();
#pragma unroll
    for (int i = 0; i < 8; i++) {              // rows w + 4i (wave-uniform)
        int row = w + (i << 2);
        int k = kk[row];
        float4 v = ((const float4*)(E + ((size_t)k << 8)))[lane];
        Eg4[(row << 6) + (lane ^ row)] = v;
    }
    __syncthreads();
    float lsum = 0.f;
    const float* zb = z + ((size_t)b << 18);
    float* ob = out + ((size_t)b << 18);
    int hwl = tid & 31, dq0 = tid >> 5;        // dq0: 0..7
    int hwp = hw0 + hwl;
#pragma unroll
    for (int i = 0; i < 8; i++) {
        int dq = dq0 + (i << 3);
        float4 ev = Eg4[(hwl << 6) + (dq ^ hwl)];
        size_t o = ((size_t)dq << 12) + hwp;   // (4*dq)*1024 + hwp
        float z0 = zb[o], z1 = zb[o + 1024], z2 = zb[o + 2048], z3 = zb[o + 3072];
        ob[o] = ev.x; ob[o + 1024] = ev.y; ob[o + 2048] = ev.z; ob[o + 3072] = ev.w;
        float dx = ev.x - z0, dy = ev.y - z1, dz2 = ev.z - z2, dw = ev.w - z3;
        lsum += dx * dx + dy * dy + dz2 * dz2 + dw * dw;
    }
#pragma unroll
    for (int off = 1; off < 64; off <<= 1) lsum += __shfl_xor(lsum, off);
    if (lane == 0) w4[w] = lsum;
    __syncthreads();
    if (tid == 0) atomicAdd(accum, w4[0] + w4[1] + w4[2] + w4[3]);
}

// ---- Kernel 5: scalar outputs ----------------------------------------------
__global__ void k_loss(const float* __restrict__ accum, float* __restrict__ out) {
    if (threadIdx.x == 0) {
        float s = accum[0] * (1.0f / 8388608.0f);
        out[8388608] = 1.25f * s;
        out[8388609] = s;
        out[8388610] = s;
    }
}

extern "C" void kernel_launch(void* const* d_in, const int* in_sizes, int n_in,
                              void* d_out, int out_size, void* d_ws, size_t ws_size,
                              hipStream_t stream) {
    const float* z = (const float*)d_in[0];
    const float* E = (const float*)d_in[1];
    char* ws = (char*)d_ws;
    unsigned short*     Abf   = (unsigned short*)(ws);               // 16,777,216 B
    v8s*                Esw   = (v8s*)(ws + 16777216);               //    524,288 B
    float*              nE    = (float*)(ws + 17301504);             //      4,096 B
    unsigned long long* cand  = (unsigned long long*)(ws + 17305600);// 1,048,576 B
    float*              accum = (float*)(ws + 18354176);             //          4 B
    float* out = (float*)d_out;

    hipLaunchKernelGGL(k_prep_e, dim3(64),   dim3(256), 0, stream, E, Esw, nE, accum);
    hipLaunchKernelGGL(k_prep_a, dim3(512),  dim3(512), 0, stream, z, Abf);
    hipLaunchKernelGGL(k_main,   dim3(512),  dim3(256), 0, stream, Abf, Esw, nE, cand);
    hipLaunchKernelGGL(k_out,    dim3(1024), dim3(256), 0, stream, z, E, cand, out, accum);
    hipLaunchKernelGGL(k_loss,   dim3(1),    dim3(64),  0, stream, accum, out);
}